// Round 7
// baseline (386.124 us; speedup 1.0000x reference)
//
#include <hip/hip_runtime.h>
#include <hip/hip_bf16.h>

// SimpleFuzzyAttention: B=2, S=2048, D=1024, H=16, DK=64
// fz(s) is univariate -> packed bf16 (v0, delta) LUT of g(s)=exp(fz(s)-bound);
// bound = 16/temp (analytic max of fz); constant cancels in softmax.
// R10: occupancy fix for flash. LUT duplication dropped (R9 measured: conflicts
// EXACTLY unchanged at 7.99M -> LDS processes wave64 as two 32-lane phases, so
// lane-half copies never collided anyway). LDS 33.3 -> 24.5 KB => 6 blocks/CU,
// launch_bounds(256,6). LUT entry = (bf16 v0, bf16 delta): kills the per-score
// v1-v0 sub. phi(r)=(r^(r>>3))&7 K/V swizzle kept (frag reads conflict-free).

#define S_LEN 2048
#define DMODEL 1024
#define NHEAD 16
#define DKH 64
#define NLUT 2048
#define LUT_MIN (-10.0f)
#define LUT_MAX (10.0f)

typedef __attribute__((ext_vector_type(8))) short bfx8;   // 8 bf16 (4 VGPRs)
typedef __attribute__((ext_vector_type(4))) float fx4;    // MFMA C/D 16x16
typedef __attribute__((ext_vector_type(16))) float fx16;  // MFMA C/D 32x32
typedef __attribute__((ext_vector_type(4))) unsigned ux4;

__device__ __forceinline__ short f2bf(float x) {
    unsigned u = __builtin_bit_cast(unsigned, x);
    u = (u + 0x7fffu + ((u >> 16) & 1u)) >> 16;   // RNE
    return (short)u;
}

__device__ __forceinline__ unsigned cvt_pk_bf16(float lo, float hi) {
    unsigned r;
    asm("v_cvt_pk_bf16_f32 %0, %1, %2" : "=v"(r) : "v"(lo), "v"(hi));
    return r;
}

// v_permlane32_swap_b32: after, a = {a_lo, b_lo}, b = {a_hi, b_hi}.
__device__ __forceinline__ void plane_swap(unsigned& a, unsigned& b) {
    asm volatile("v_permlane32_swap_b32 %0, %1" : "+v"(a), "+v"(b));
}

__device__ __forceinline__ void stage8_f32(const float* __restrict__ src, short* dst) {
    float4 a = *(const float4*)(src);
    float4 b = *(const float4*)(src + 4);
    bfx8 r;
    r[0] = f2bf(a.x); r[1] = f2bf(a.y); r[2] = f2bf(a.z); r[3] = f2bf(a.w);
    r[4] = f2bf(b.x); r[5] = f2bf(b.y); r[6] = f2bf(b.z); r[7] = f2bf(b.w);
    *(bfx8*)dst = r;
}

// global -> LDS direct 16B copy (LDS base wave-uniform; lane*16 implied)
__device__ __forceinline__ void gload_lds16(const void* g, void* l) {
    __builtin_amdgcn_global_load_lds(
        (const __attribute__((address_space(1))) unsigned int*)g,
        (__attribute__((address_space(3))) unsigned int*)l, 16, 0, 0);
}

// ---------------------------------------------------------------------------
// Parallel LUT slice: 8 blocks x 256 points. lutp[j] = bf16(g[j]) |
// bf16(g[j+1]-g[j])<<16, g = exp(fz - 16/temp). No division, no reduction.
// ---------------------------------------------------------------------------
__device__ void lut_slice(const float* __restrict__ centers, const float* __restrict__ widths,
                          const float* __restrict__ temp, unsigned* __restrict__ lutp,
                          int slice) {
    __shared__ float cs[48], iw[48];
    __shared__ float gsh[257];
    int tid = threadIdx.x;
    if (tid < 48) {
        cs[tid] = centers[tid];
        float w = widths[tid];
        iw[tid] = -0.5f / (w * w);
    }
    __syncthreads();
    float invT = 1.0f / temp[0];
    const float step = (LUT_MAX - LUT_MIN) / (float)(NLUT - 1);
    float bound = 16.0f * invT;
    int base = slice * 256;
    #pragma unroll 1
    for (int idx = tid; idx < 257; idx += 256) {   // tid 0 also does the halo
        int i = base + idx; if (i > NLUT - 1) i = NLUT - 1;
        float s = LUT_MIN + step * (float)i;
        float a = 0.0f;
        #pragma unroll
        for (int j = 0; j < 48; j++) {
            float d = s - cs[j];
            a += expf(d * d * iw[j]);
        }
        float fz = a * (1.0f / 3.0f) * invT;
        gsh[idx] = expf(fz - bound);
    }
    __syncthreads();
    float g0 = gsh[tid];
    unsigned lo = (unsigned short)f2bf(g0);
    unsigned hi = (unsigned short)f2bf(gsh[tid + 1] - g0);
    lutp[base + tid] = lo | (hi << 16);
}

__global__ void build_lut_pk(const float* centers, const float* widths,
                             const float* temp, unsigned* lutp) {
    lut_slice(centers, widths, temp, lutp, blockIdx.x);
}

// ---------------------------------------------------------------------------
// fp32 -> bf16 cast (fallback path), 8 elems/thread
// ---------------------------------------------------------------------------
__global__ void cast_bf16(const float* __restrict__ src, short* __restrict__ dst, int n8) {
    int i = blockIdx.x * 256 + threadIdx.x;
    if (i < n8) stage8_f32(src + (size_t)i * 8, dst + (size_t)i * 8);
}

// ---------------------------------------------------------------------------
// Fused prep: grid 1032. Blocks [0,1024) grid-stride the 8192 copy units
// ([0,6144)=inputs, [6144,8192)=weights); blocks [1024,1032) build the LUT.
// ---------------------------------------------------------------------------
__global__ void prep_all(const float* q, const float* kin, const float* v,
        const float* wq, const float* wk, const float* wv, const float* wo,
        short* xq, short* xk, short* xv,
        short* bwq, short* bwk, short* bwv, short* bwo,
        const float* centers, const float* widths, const float* temp,
        unsigned* lutp) {
    int bid = blockIdx.x;
    if (bid >= 1024) {
        lut_slice(centers, widths, temp, lutp, bid - 1024);
        return;
    }
    for (int vb = bid; vb < 8192; vb += 1024) {
        const float* src; short* dst; int blk;
        if (vb < 6144) {
            int y = vb >> 11; blk = vb & 2047;
            src = (y == 0) ? q : (y == 1) ? kin : v;
            dst = (y == 0) ? xq : (y == 1) ? xk : xv;
        } else {
            int y = (vb - 6144) >> 9; blk = (vb - 6144) & 511;
            src = (y == 0) ? wq : (y == 1) ? wk : (y == 2) ? wv : wo;
            dst = (y == 0) ? bwq : (y == 1) ? bwk : (y == 2) ? bwv : bwo;
        }
        size_t i = (size_t)blk * 256 + threadIdx.x;   // always in range (exact)
        stage8_f32(src + i * 8, (short*)dst + i * 8);
    }
}

// ---------------------------------------------------------------------------
// bf16 BT-GEMM, 128x128 tile, BK=32, double-buffered, launch_bounds(256,3).
// C[m,n] = (sum_k A[m,k]*W[n,k] + bias[n]) * scale.
// mode 0: bf16 [B,H,S,DK]; 1: bf16 [B,H,DK,S]; 2: fp32 [M,N]
// ---------------------------------------------------------------------------
struct GemmJob {
    const short* A; const short* W; const float* bias;
    short* obf; float* of32; int mode; float scale;
};

__global__ __launch_bounds__(256, 3) void gemm128(GemmJob j0, GemmJob j1, GemmJob j2) {
    __shared__ __align__(16) short As[2][128 * 32];   // 2 x 8 KB, swizzled
    __shared__ __align__(16) short Bs[2][128 * 32];   // 2 x 8 KB
    GemmJob jb = (blockIdx.z == 0) ? j0 : (blockIdx.z == 1) ? j1 : j2;
    int tid = threadIdx.x, wave = tid >> 6, lane = tid & 63, quad = lane >> 4, l15 = lane & 15;
    int m0 = blockIdx.y * 128, n0 = blockIdx.x * 128;
    int wm = (wave >> 1) * 64, wn = (wave & 1) * 64;

    fx4 acc[4][4];
    #pragma unroll
    for (int i = 0; i < 4; i++)
        #pragma unroll
        for (int j = 0; j < 4; j++)
            #pragma unroll
            for (int r = 0; r < 4; r++) acc[i][j][r] = 0.0f;

    int fc = (quad ^ ((l15 >> 1) & 3)) * 8;        // swizzled frag chunk (shorts)

    // staging lane geometry (constant): 512 slots of 16B per buffer
    int srow[2], sgc[2];
    #pragma unroll
    for (int r = 0; r < 2; r++) {
        int slot = r * 256 + wave * 64 + lane;     // -> 128 rows x 4 chunks
        srow[r] = slot >> 2;
        sgc[r] = (slot & 3) ^ ((srow[r] >> 1) & 3);
    }

    auto stage = [&](int k0, int buf) {
        #pragma unroll
        for (int r = 0; r < 2; r++) {
            gload_lds16(jb.A + (size_t)(m0 + srow[r]) * DMODEL + k0 + sgc[r] * 8,
                        &As[buf][(r * 256 + wave * 64) * 8]);
            gload_lds16(jb.W + (size_t)(n0 + srow[r]) * DMODEL + k0 + sgc[r] * 8,
                        &Bs[buf][(r * 256 + wave * 64) * 8]);
        }
    };

    stage(0, 0);
    __syncthreads();                 // vmcnt(0) drain of prologue stage
    int buf = 0;
    for (int k0 = 0; k0 < DMODEL; k0 += 32) {
        if (k0 + 32 < DMODEL) stage(k0 + 32, buf ^ 1);   // prefetch next tile
        bfx8 af[4], bfr[4];
        #pragma unroll
        for (int i = 0; i < 4; i++) af[i] = *(const bfx8*)(&As[buf][(wm + i * 16 + l15) * 32 + fc]);
        #pragma unroll
        for (int j = 0; j < 4; j++) bfr[j] = *(const bfx8*)(&Bs[buf][(wn + j * 16 + l15) * 32 + fc]);
        #pragma unroll
        for (int i = 0; i < 4; i++)
            #pragma unroll
            for (int j = 0; j < 4; j++)
                acc[i][j] = __builtin_amdgcn_mfma_f32_16x16x32_bf16(af[i], bfr[j], acc[i][j], 0, 0, 0);
        __syncthreads();             // drains prefetch (had full compute to fly)
        buf ^= 1;
    }

    // epilogue: C/D layout col=lane&15 (n), row=quad*4+reg (m)
    #pragma unroll
    for (int j = 0; j < 4; j++) {
        int n = n0 + wn + j * 16 + l15;
        float bv = jb.bias[n];
        #pragma unroll
        for (int i = 0; i < 4; i++) {
            #pragma unroll
            for (int r = 0; r < 4; r++) {
                int m = m0 + wm + i * 16 + quad * 4 + r;
                float v = (acc[i][j][r] + bv) * jb.scale;
                if (jb.mode == 0) {
                    int b = m >> 11, s = m & 2047, h = n >> 6, dk = n & 63;
                    jb.obf[(((size_t)(b * NHEAD + h)) * S_LEN + s) * DKH + dk] = f2bf(v);
                } else if (jb.mode == 1) {
                    int b = m >> 11, s = m & 2047, h = n >> 6, dk = n & 63;
                    jb.obf[(((size_t)(b * NHEAD + h)) * DKH + dk) * S_LEN + s] = f2bf(v);
                } else {
                    jb.of32[(size_t)m * DMODEL + n] = v;
                }
            }
        }
    }
}

// ---------------------------------------------------------------------------
// Fuzzy flash attention, R10: 32x32x16 MFMA, in-register P; K AND V staged in
// LDS with phi(r)=(r^(r>>3))&7 chunk swizzle (fragment reads conflict-free);
// single LUT copy (24.5 KB LDS total -> 6 blocks/CU); den via ones-MFMA.
// Block = 64 q rows of one (b,h); wave (wq, st) owns a 32q x 32kv quadrant.
// ---------------------------------------------------------------------------
__global__ __launch_bounds__(256, 6) void flash_fuzzy(const short* __restrict__ Qb,
        const short* __restrict__ Kb, const short* __restrict__ VTb,
        const unsigned* __restrict__ lutg, short* __restrict__ AO) {
    __shared__ __align__(16) short Ks[64 * 64];     // 8 KB [kv][dk], phi-swizzled
    __shared__ __align__(16) short Vs[64 * 64];     // 8 KB [dk][kv], phi-swizzled
    __shared__ unsigned lut[NLUT];                  // 8 KB (v0, delta) bf16 pairs
    __shared__ float dbuf[128];                     // den exchange

    int tid = threadIdx.x, wave = tid >> 6, lane = tid & 63;
    int l31 = lane & 31, hi = lane >> 5;
    int wq = wave >> 1, st = wave & 1;
    int q0 = blockIdx.x * 64, bh = blockIdx.y;
    const short* Qp = Qb + (size_t)bh * S_LEN * DKH;
    const short* Kp = Kb + (size_t)bh * S_LEN * DKH;
    const short* Vp = VTb + (size_t)bh * DKH * S_LEN;

    #pragma unroll
    for (int i = tid; i < NLUT / 4; i += 256)
        ((uint4*)lut)[i] = ((const uint4*)lutg)[i];

    // Q as B-operand: lane supplies B[k=hi*8+j][q=l31] = Q[q0+wq*32+l31][k]
    bfx8 aq[4];
    #pragma unroll
    for (int ks = 0; ks < 4; ks++)
        aq[ks] = *(const bfx8*)(Qp + (size_t)(q0 + wq * 32 + l31) * DKH + ks * 16 + hi * 8);

    bfx8 ones;
    #pragma unroll
    for (int i = 0; i < 8; i++) ones[i] = (short)0x3F80;  // bf16 1.0

    fx16 oacc[2];
    fx16 dacc;
    #pragma unroll
    for (int r = 0; r < 16; r++) dacc[r] = 0.0f;
    #pragma unroll
    for (int dt = 0; dt < 2; dt++)
        #pragma unroll
        for (int r = 0; r < 16; r++) oacc[dt][r] = 0.0f;

    const float invh = (float)(NLUT - 1) / (LUT_MAX - LUT_MIN);
    const float xoff = -LUT_MIN * invh;

    // staging geometry: 512 slots of 16B per buffer, 2 per thread;
    // chunk swizzled by phi(row) = (row ^ (row>>3)) & 7
    int srow[2], sgc[2];
    #pragma unroll
    for (int r = 0; r < 2; r++) {
        int slot = (wave * 2 + r) * 64 + lane;
        srow[r] = slot >> 3;
        sgc[r] = (slot & 7) ^ ((srow[r] ^ (srow[r] >> 3)) & 7);
    }

    int krow = st * 32 + l31;
    int kphi = (krow ^ (krow >> 3)) & 7;

    for (int t0 = 0; t0 < S_LEN; t0 += 64) {
        __syncthreads();                 // all waves done reading tile t0-64
        #pragma unroll
        for (int r = 0; r < 2; r++) {
            gload_lds16(Kp + (size_t)(t0 + srow[r]) * DKH + sgc[r] * 8,
                        &Ks[((wave * 2 + r) * 64) * 8]);
            gload_lds16(Vp + (size_t)srow[r] * S_LEN + t0 + sgc[r] * 8,
                        &Vs[((wave * 2 + r) * 64) * 8]);
        }
        __syncthreads();                 // staging complete

        // S^T[kv32 (this wave's half)][q32] = K . Q^T over dk=64 (4 k-steps)
        fx16 sac;
        #pragma unroll
        for (int r = 0; r < 16; r++) sac[r] = 0.0f;
        #pragma unroll
        for (int ks = 0; ks < 4; ks++) {
            bfx8 kf = *(const bfx8*)(&Ks[krow * 64 + (((ks * 2 + hi) ^ kphi) * 8)]);
            sac = __builtin_amdgcn_mfma_f32_32x32x16_bf16(kf, aq[ks], sac, 0, 0, 0);
        }

        // p = g(s): one b32 (v0, delta) gather + fma lerp; pack pairs to bf16
        unsigned w[8];
        #pragma unroll
        for (int t = 0; t < 8; t++) {
            float pv[2];
            #pragma unroll
            for (int u = 0; u < 2; u++) {
                float s = sac[t * 2 + u];
                float x = fmaf(s, invh, xoff);
                x = __builtin_amdgcn_fmed3f(x, 0.0f, (float)(NLUT - 1));
                int j = (int)x;
                float f = x - (float)j;
                unsigned pr = lut[j];
                float v0 = __builtin_bit_cast(float, pr << 16);
                float dl = __builtin_bit_cast(float, pr & 0xffff0000u);
                pv[u] = fmaf(f, dl, v0);
            }
            w[t] = cvt_pk_bf16(pv[0], pv[1]);
        }

        // redistribute across lane halves -> PV B-fragments
        plane_swap(w[0], w[2]); plane_swap(w[1], w[3]);
        plane_swap(w[4], w[6]); plane_swap(w[5], w[7]);
        ux4 b0v = {w[0], w[1], w[2], w[3]};
        ux4 b1v = {w[4], w[5], w[6], w[7]};
        bfx8 pb0 = __builtin_bit_cast(bfx8, b0v);
        bfx8 pb1 = __builtin_bit_cast(bfx8, b1v);

        // O^T[dk][q] += VT . P^T   (2 dk-tiles x 2 k-steps)
        #pragma unroll
        for (int dt = 0; dt < 2; dt++) {
            int row = dt * 32 + l31;
            int vphi = (row ^ (row >> 3)) & 7;
            bfx8 v0f = *(const bfx8*)(&Vs[row * 64 + (((st * 4 + 0 + hi) ^ vphi) * 8)]);
            bfx8 v1f = *(const bfx8*)(&Vs[row * 64 + (((st * 4 + 2 + hi) ^ vphi) * 8)]);
            oacc[dt] = __builtin_amdgcn_mfma_f32_32x32x16_bf16(v0f, pb0, oacc[dt], 0, 0, 0);
            oacc[dt] = __builtin_amdgcn_mfma_f32_32x32x16_bf16(v1f, pb1, oacc[dt], 0, 0, 0);
        }
        // den[q] += sum_kv P[kv][q] on the matrix pipe (rows all equal)
        dacc = __builtin_amdgcn_mfma_f32_32x32x16_bf16(ones, pb0, dacc, 0, 0, 0);
        dacc = __builtin_amdgcn_mfma_f32_32x32x16_bf16(ones, pb1, dacc, 0, 0, 0);
    }

    float den = dacc[0];   // den[q=l31] for this wave's kv-half (rows equal)

    // combine kv halves: st=1 waves stash to LDS (Ks/Vs dead), st=0 finalize
    __syncthreads();
    float* obuf = (wq == 0) ? (float*)Ks : (float*)Vs;   // 8 KB each
    if (st == 1) {
        #pragma unroll
        for (int dt = 0; dt < 2; dt++)
            #pragma unroll
            for (int r = 0; r < 16; r++)
                obuf[(dt * 16 + r) * 64 + lane] = oacc[dt][r];
        dbuf[wq * 64 + lane] = den;
    }
    __syncthreads();
    if (st == 0) {
        float dtot = den + dbuf[wq * 64 + lane];
        int b = bh >> 4, h = bh & 15;
        #pragma unroll
        for (int dt = 0; dt < 2; dt++) {
            #pragma unroll
            for (int r = 0; r < 16; r++) {
                float o = oacc[dt][r] + obuf[(dt * 16 + r) * 64 + lane];
                int dk = dt * 32 + (r & 3) + 8 * (r >> 2) + 4 * hi;
                int q = q0 + wq * 32 + l31;
                AO[((size_t)(b * S_LEN + q)) * DMODEL + h * DKH + dk] = f2bf(o / dtot);
            }
        }
    }
}

// ---------------------------------------------------------------------------
extern "C" void kernel_launch(void* const* d_in, const int* in_sizes, int n_in,
                              void* d_out, int out_size, void* d_ws, size_t ws_size,
                              hipStream_t stream) {
    const float* query   = (const float*)d_in[0];
    const float* key_in  = (const float*)d_in[1];
    const float* value   = (const float*)d_in[2];
    const float* w_q     = (const float*)d_in[3];
    const float* b_q     = (const float*)d_in[4];
    const float* w_k     = (const float*)d_in[5];
    const float* b_k     = (const float*)d_in[6];
    const float* w_v     = (const float*)d_in[7];
    const float* b_v     = (const float*)d_in[8];
    const float* w_o     = (const float*)d_in[9];
    const float* b_o     = (const float*)d_in[10];
    const float* centers = (const float*)d_in[11];
    const float* widths  = (const float*)d_in[12];
    const float* temp    = (const float*)d_in[13];

    char* p = (char*)d_ws;
    auto alloc = [&](size_t bytes) -> void* {
        void* r = (void*)p;
        p += (bytes + 255) & ~(size_t)255;
        return r;
    };
    const size_t nBHSD = (size_t)2 * NHEAD * S_LEN * DKH;    // 4.19M elems
    const size_t nW    = (size_t)DMODEL * DMODEL;            // 1.05M elems
    unsigned* lutp = (unsigned*)alloc(NLUT * 4);
    short* Qb  = (short*)alloc(nBHSD * 2);
    short* Kb  = (short*)alloc(nBHSD * 2);
    short* VTb = (short*)alloc(nBHSD * 2);

    char* save = p;
    short* xq  = (short*)alloc(nBHSD * 2);
    short* xk  = (short*)alloc(nBHSD * 2);
    short* xv  = (short*)alloc(nBHSD * 2);
    short* bwq = (short*)alloc(nW * 2);
    short* bwk = (short*)alloc(nW * 2);
    short* bwv = (short*)alloc(nW * 2);
    short* bwo = (short*)alloc(nW * 2);
    bool fused = ((size_t)(p - (char*)d_ws) <= ws_size);

    dim3 blk(256);
    dim3 gq(8, 32, 3), g1(8, 32, 1), fg(32, 32);
    GemmJob JO;

    if (fused) {
        short* AO = xq;   // alias: xq dead after QKV gemm
        prep_all<<<dim3(1032), blk, 0, stream>>>(query, key_in, value, w_q, w_k, w_v, w_o,
                xq, xk, xv, bwq, bwk, bwv, bwo, centers, widths, temp, lutp);
        GemmJob JQ = {xq, bwq, b_q, Qb,  nullptr, 0, 0.125f};   // 1/sqrt(64) folded
        GemmJob JK = {xk, bwk, b_k, Kb,  nullptr, 0, 1.0f};
        GemmJob JV = {xv, bwv, b_v, VTb, nullptr, 1, 1.0f};
        gemm128<<<gq, blk, 0, stream>>>(JQ, JK, JV);
        flash_fuzzy<<<fg, blk, 0, stream>>>(Qb, Kb, VTb, lutp, AO);
        JO = {AO, bwo, b_o, nullptr, (float*)d_out, 2, 1.0f};
        gemm128<<<g1, blk, 0, stream>>>(JO, JO, JO);
    } else {
        // serial fallback: reuse one x-buffer + one w-buffer (~36 MB total)
        p = save;
        short* xf = (short*)alloc(nBHSD * 2);
        short* wb = (short*)alloc(nW * 2);
        short* AO = xf;
        const int n8x = (int)(nBHSD / 8), n8w = (int)(nW / 8);
        dim3 cg((n8x + 255) / 256), cw((n8w + 255) / 256);
        build_lut_pk<<<dim3(8), blk, 0, stream>>>(centers, widths, temp, lutp);
        cast_bf16<<<cg, blk, 0, stream>>>(query, xf, n8x);
        cast_bf16<<<cw, blk, 0, stream>>>(w_q, wb, n8w);
        JO = {xf, wb, b_q, Qb, nullptr, 0, 0.125f};
        gemm128<<<g1, blk, 0, stream>>>(JO, JO, JO);
        cast_bf16<<<cg, blk, 0, stream>>>(key_in, xf, n8x);
        cast_bf16<<<cw, blk, 0, stream>>>(w_k, wb, n8w);
        JO = {xf, wb, b_k, Kb, nullptr, 0, 1.0f};
        gemm128<<<g1, blk, 0, stream>>>(JO, JO, JO);
        cast_bf16<<<cg, blk, 0, stream>>>(value, xf, n8x);
        cast_bf16<<<cw, blk, 0, stream>>>(w_v, wb, n8w);
        JO = {xf, wb, b_v, VTb, nullptr, 1, 1.0f};
        gemm128<<<g1, blk, 0, stream>>>(JO, JO, JO);
        flash_fuzzy<<<fg, blk, 0, stream>>>(Qb, Kb, VTb, lutp, AO);
        cast_bf16<<<cw, blk, 0, stream>>>(w_o, wb, n8w);
        JO = {AO, wb, b_o, nullptr, (float*)d_out, 2, 1.0f};
        gemm128<<<g1, blk, 0, stream>>>(JO, JO, JO);
    }
}

// Round 8
// 259.901 us; speedup vs baseline: 1.4857x; 1.4857x over previous
//
#include <hip/hip_runtime.h>
#include <hip/hip_bf16.h>

// SimpleFuzzyAttention: B=2, S=2048, D=1024, H=16, DK=64
// fz(s) is univariate -> packed bf16 (v0, delta) LUT of g(s)=exp(fz(s)-bound);
// bound = 16/temp (analytic max of fz); constant cancels in softmax.
// R11: fix R10's spill disaster. launch_bounds(256,6) forced VGPR 64->40 and
// spilled the accumulators to scratch (FETCH 69.7->414 MB, WRITE 8->236 MB).
// Revert to launch_bounds(256,4): the 2nd arg only caps registers; occupancy
// comes from LDS, and the 24.5 KB footprint already allows 6 blocks/CU at the
// natural VGPR=64 (8 waves/SIMD HW limit). Everything else = R10 (single LUT,
// (v0,delta) entries, phi(r)=(r^(r>>3))&7 K/V swizzle, den via ones-MFMA).

#define S_LEN 2048
#define DMODEL 1024
#define NHEAD 16
#define DKH 64
#define NLUT 2048
#define LUT_MIN (-10.0f)
#define LUT_MAX (10.0f)

typedef __attribute__((ext_vector_type(8))) short bfx8;   // 8 bf16 (4 VGPRs)
typedef __attribute__((ext_vector_type(4))) float fx4;    // MFMA C/D 16x16
typedef __attribute__((ext_vector_type(16))) float fx16;  // MFMA C/D 32x32
typedef __attribute__((ext_vector_type(4))) unsigned ux4;

__device__ __forceinline__ short f2bf(float x) {
    unsigned u = __builtin_bit_cast(unsigned, x);
    u = (u + 0x7fffu + ((u >> 16) & 1u)) >> 16;   // RNE
    return (short)u;
}

__device__ __forceinline__ unsigned cvt_pk_bf16(float lo, float hi) {
    unsigned r;
    asm("v_cvt_pk_bf16_f32 %0, %1, %2" : "=v"(r) : "v"(lo), "v"(hi));
    return r;
}

// v_permlane32_swap_b32: after, a = {a_lo, b_lo}, b = {a_hi, b_hi}.
__device__ __forceinline__ void plane_swap(unsigned& a, unsigned& b) {
    asm volatile("v_permlane32_swap_b32 %0, %1" : "+v"(a), "+v"(b));
}

__device__ __forceinline__ void stage8_f32(const float* __restrict__ src, short* dst) {
    float4 a = *(const float4*)(src);
    float4 b = *(const float4*)(src + 4);
    bfx8 r;
    r[0] = f2bf(a.x); r[1] = f2bf(a.y); r[2] = f2bf(a.z); r[3] = f2bf(a.w);
    r[4] = f2bf(b.x); r[5] = f2bf(b.y); r[6] = f2bf(b.z); r[7] = f2bf(b.w);
    *(bfx8*)dst = r;
}

// global -> LDS direct 16B copy (LDS base wave-uniform; lane*16 implied)
__device__ __forceinline__ void gload_lds16(const void* g, void* l) {
    __builtin_amdgcn_global_load_lds(
        (const __attribute__((address_space(1))) unsigned int*)g,
        (__attribute__((address_space(3))) unsigned int*)l, 16, 0, 0);
}

// ---------------------------------------------------------------------------
// Parallel LUT slice: 8 blocks x 256 points. lutp[j] = bf16(g[j]) |
// bf16(g[j+1]-g[j])<<16, g = exp(fz - 16/temp). No division, no reduction.
// ---------------------------------------------------------------------------
__device__ void lut_slice(const float* __restrict__ centers, const float* __restrict__ widths,
                          const float* __restrict__ temp, unsigned* __restrict__ lutp,
                          int slice) {
    __shared__ float cs[48], iw[48];
    __shared__ float gsh[257];
    int tid = threadIdx.x;
    if (tid < 48) {
        cs[tid] = centers[tid];
        float w = widths[tid];
        iw[tid] = -0.5f / (w * w);
    }
    __syncthreads();
    float invT = 1.0f / temp[0];
    const float step = (LUT_MAX - LUT_MIN) / (float)(NLUT - 1);
    float bound = 16.0f * invT;
    int base = slice * 256;
    #pragma unroll 1
    for (int idx = tid; idx < 257; idx += 256) {   // tid 0 also does the halo
        int i = base + idx; if (i > NLUT - 1) i = NLUT - 1;
        float s = LUT_MIN + step * (float)i;
        float a = 0.0f;
        #pragma unroll
        for (int j = 0; j < 48; j++) {
            float d = s - cs[j];
            a += expf(d * d * iw[j]);
        }
        float fz = a * (1.0f / 3.0f) * invT;
        gsh[idx] = expf(fz - bound);
    }
    __syncthreads();
    float g0 = gsh[tid];
    unsigned lo = (unsigned short)f2bf(g0);
    unsigned hi = (unsigned short)f2bf(gsh[tid + 1] - g0);
    lutp[base + tid] = lo | (hi << 16);
}

__global__ void build_lut_pk(const float* centers, const float* widths,
                             const float* temp, unsigned* lutp) {
    lut_slice(centers, widths, temp, lutp, blockIdx.x);
}

// ---------------------------------------------------------------------------
// fp32 -> bf16 cast (fallback path), 8 elems/thread
// ---------------------------------------------------------------------------
__global__ void cast_bf16(const float* __restrict__ src, short* __restrict__ dst, int n8) {
    int i = blockIdx.x * 256 + threadIdx.x;
    if (i < n8) stage8_f32(src + (size_t)i * 8, dst + (size_t)i * 8);
}

// ---------------------------------------------------------------------------
// Fused prep: grid 1032. Blocks [0,1024) grid-stride the 8192 copy units
// ([0,6144)=inputs, [6144,8192)=weights); blocks [1024,1032) build the LUT.
// ---------------------------------------------------------------------------
__global__ void prep_all(const float* q, const float* kin, const float* v,
        const float* wq, const float* wk, const float* wv, const float* wo,
        short* xq, short* xk, short* xv,
        short* bwq, short* bwk, short* bwv, short* bwo,
        const float* centers, const float* widths, const float* temp,
        unsigned* lutp) {
    int bid = blockIdx.x;
    if (bid >= 1024) {
        lut_slice(centers, widths, temp, lutp, bid - 1024);
        return;
    }
    for (int vb = bid; vb < 8192; vb += 1024) {
        const float* src; short* dst; int blk;
        if (vb < 6144) {
            int y = vb >> 11; blk = vb & 2047;
            src = (y == 0) ? q : (y == 1) ? kin : v;
            dst = (y == 0) ? xq : (y == 1) ? xk : xv;
        } else {
            int y = (vb - 6144) >> 9; blk = (vb - 6144) & 511;
            src = (y == 0) ? wq : (y == 1) ? wk : (y == 2) ? wv : wo;
            dst = (y == 0) ? bwq : (y == 1) ? bwk : (y == 2) ? bwv : bwo;
        }
        size_t i = (size_t)blk * 256 + threadIdx.x;   // always in range (exact)
        stage8_f32(src + i * 8, (short*)dst + i * 8);
    }
}

// ---------------------------------------------------------------------------
// bf16 BT-GEMM, 128x128 tile, BK=32, double-buffered, launch_bounds(256,3).
// C[m,n] = (sum_k A[m,k]*W[n,k] + bias[n]) * scale.
// mode 0: bf16 [B,H,S,DK]; 1: bf16 [B,H,DK,S]; 2: fp32 [M,N]
// ---------------------------------------------------------------------------
struct GemmJob {
    const short* A; const short* W; const float* bias;
    short* obf; float* of32; int mode; float scale;
};

__global__ __launch_bounds__(256, 3) void gemm128(GemmJob j0, GemmJob j1, GemmJob j2) {
    __shared__ __align__(16) short As[2][128 * 32];   // 2 x 8 KB, swizzled
    __shared__ __align__(16) short Bs[2][128 * 32];   // 2 x 8 KB
    GemmJob jb = (blockIdx.z == 0) ? j0 : (blockIdx.z == 1) ? j1 : j2;
    int tid = threadIdx.x, wave = tid >> 6, lane = tid & 63, quad = lane >> 4, l15 = lane & 15;
    int m0 = blockIdx.y * 128, n0 = blockIdx.x * 128;
    int wm = (wave >> 1) * 64, wn = (wave & 1) * 64;

    fx4 acc[4][4];
    #pragma unroll
    for (int i = 0; i < 4; i++)
        #pragma unroll
        for (int j = 0; j < 4; j++)
            #pragma unroll
            for (int r = 0; r < 4; r++) acc[i][j][r] = 0.0f;

    int fc = (quad ^ ((l15 >> 1) & 3)) * 8;        // swizzled frag chunk (shorts)

    // staging lane geometry (constant): 512 slots of 16B per buffer
    int srow[2], sgc[2];
    #pragma unroll
    for (int r = 0; r < 2; r++) {
        int slot = r * 256 + wave * 64 + lane;     // -> 128 rows x 4 chunks
        srow[r] = slot >> 2;
        sgc[r] = (slot & 3) ^ ((srow[r] >> 1) & 3);
    }

    auto stage = [&](int k0, int buf) {
        #pragma unroll
        for (int r = 0; r < 2; r++) {
            gload_lds16(jb.A + (size_t)(m0 + srow[r]) * DMODEL + k0 + sgc[r] * 8,
                        &As[buf][(r * 256 + wave * 64) * 8]);
            gload_lds16(jb.W + (size_t)(n0 + srow[r]) * DMODEL + k0 + sgc[r] * 8,
                        &Bs[buf][(r * 256 + wave * 64) * 8]);
        }
    };

    stage(0, 0);
    __syncthreads();                 // vmcnt(0) drain of prologue stage
    int buf = 0;
    for (int k0 = 0; k0 < DMODEL; k0 += 32) {
        if (k0 + 32 < DMODEL) stage(k0 + 32, buf ^ 1);   // prefetch next tile
        bfx8 af[4], bfr[4];
        #pragma unroll
        for (int i = 0; i < 4; i++) af[i] = *(const bfx8*)(&As[buf][(wm + i * 16 + l15) * 32 + fc]);
        #pragma unroll
        for (int j = 0; j < 4; j++) bfr[j] = *(const bfx8*)(&Bs[buf][(wn + j * 16 + l15) * 32 + fc]);
        #pragma unroll
        for (int i = 0; i < 4; i++)
            #pragma unroll
            for (int j = 0; j < 4; j++)
                acc[i][j] = __builtin_amdgcn_mfma_f32_16x16x32_bf16(af[i], bfr[j], acc[i][j], 0, 0, 0);
        __syncthreads();             // drains prefetch (had full compute to fly)
        buf ^= 1;
    }

    // epilogue: C/D layout col=lane&15 (n), row=quad*4+reg (m)
    #pragma unroll
    for (int j = 0; j < 4; j++) {
        int n = n0 + wn + j * 16 + l15;
        float bv = jb.bias[n];
        #pragma unroll
        for (int i = 0; i < 4; i++) {
            #pragma unroll
            for (int r = 0; r < 4; r++) {
                int m = m0 + wm + i * 16 + quad * 4 + r;
                float v = (acc[i][j][r] + bv) * jb.scale;
                if (jb.mode == 0) {
                    int b = m >> 11, s = m & 2047, h = n >> 6, dk = n & 63;
                    jb.obf[(((size_t)(b * NHEAD + h)) * S_LEN + s) * DKH + dk] = f2bf(v);
                } else if (jb.mode == 1) {
                    int b = m >> 11, s = m & 2047, h = n >> 6, dk = n & 63;
                    jb.obf[(((size_t)(b * NHEAD + h)) * DKH + dk) * S_LEN + s] = f2bf(v);
                } else {
                    jb.of32[(size_t)m * DMODEL + n] = v;
                }
            }
        }
    }
}

// ---------------------------------------------------------------------------
// Fuzzy flash attention, R11: 32x32x16 MFMA, in-register P; K AND V staged in
// LDS with phi(r)=(r^(r>>3))&7 chunk swizzle (fragment reads conflict-free);
// single LUT copy; 24.5 KB LDS -> 6 blocks/CU at natural VGPR=64.
// launch_bounds(256,4): do NOT raise the 2nd arg (R10: 6 forced VGPR->40,
// spilled accumulators to scratch, 414 MB fetch, 2.5x regression).
// Block = 64 q rows of one (b,h); wave (wq, st) owns a 32q x 32kv quadrant.
// ---------------------------------------------------------------------------
__global__ __launch_bounds__(256, 4) void flash_fuzzy(const short* __restrict__ Qb,
        const short* __restrict__ Kb, const short* __restrict__ VTb,
        const unsigned* __restrict__ lutg, short* __restrict__ AO) {
    __shared__ __align__(16) short Ks[64 * 64];     // 8 KB [kv][dk], phi-swizzled
    __shared__ __align__(16) short Vs[64 * 64];     // 8 KB [dk][kv], phi-swizzled
    __shared__ unsigned lut[NLUT];                  // 8 KB (v0, delta) bf16 pairs
    __shared__ float dbuf[128];                     // den exchange

    int tid = threadIdx.x, wave = tid >> 6, lane = tid & 63;
    int l31 = lane & 31, hi = lane >> 5;
    int wq = wave >> 1, st = wave & 1;
    int q0 = blockIdx.x * 64, bh = blockIdx.y;
    const short* Qp = Qb + (size_t)bh * S_LEN * DKH;
    const short* Kp = Kb + (size_t)bh * S_LEN * DKH;
    const short* Vp = VTb + (size_t)bh * DKH * S_LEN;

    #pragma unroll
    for (int i = tid; i < NLUT / 4; i += 256)
        ((uint4*)lut)[i] = ((const uint4*)lutg)[i];

    // Q as B-operand: lane supplies B[k=hi*8+j][q=l31] = Q[q0+wq*32+l31][k]
    bfx8 aq[4];
    #pragma unroll
    for (int ks = 0; ks < 4; ks++)
        aq[ks] = *(const bfx8*)(Qp + (size_t)(q0 + wq * 32 + l31) * DKH + ks * 16 + hi * 8);

    bfx8 ones;
    #pragma unroll
    for (int i = 0; i < 8; i++) ones[i] = (short)0x3F80;  // bf16 1.0

    fx16 oacc[2];
    fx16 dacc;
    #pragma unroll
    for (int r = 0; r < 16; r++) dacc[r] = 0.0f;
    #pragma unroll
    for (int dt = 0; dt < 2; dt++)
        #pragma unroll
        for (int r = 0; r < 16; r++) oacc[dt][r] = 0.0f;

    const float invh = (float)(NLUT - 1) / (LUT_MAX - LUT_MIN);
    const float xoff = -LUT_MIN * invh;

    // staging geometry: 512 slots of 16B per buffer, 2 per thread;
    // chunk swizzled by phi(row) = (row ^ (row>>3)) & 7
    int srow[2], sgc[2];
    #pragma unroll
    for (int r = 0; r < 2; r++) {
        int slot = (wave * 2 + r) * 64 + lane;
        srow[r] = slot >> 3;
        sgc[r] = (slot & 7) ^ ((srow[r] ^ (srow[r] >> 3)) & 7);
    }

    int krow = st * 32 + l31;
    int kphi = (krow ^ (krow >> 3)) & 7;

    for (int t0 = 0; t0 < S_LEN; t0 += 64) {
        __syncthreads();                 // all waves done reading tile t0-64
        #pragma unroll
        for (int r = 0; r < 2; r++) {
            gload_lds16(Kp + (size_t)(t0 + srow[r]) * DKH + sgc[r] * 8,
                        &Ks[((wave * 2 + r) * 64) * 8]);
            gload_lds16(Vp + (size_t)srow[r] * S_LEN + t0 + sgc[r] * 8,
                        &Vs[((wave * 2 + r) * 64) * 8]);
        }
        __syncthreads();                 // staging complete

        // S^T[kv32 (this wave's half)][q32] = K . Q^T over dk=64 (4 k-steps)
        fx16 sac;
        #pragma unroll
        for (int r = 0; r < 16; r++) sac[r] = 0.0f;
        #pragma unroll
        for (int ks = 0; ks < 4; ks++) {
            bfx8 kf = *(const bfx8*)(&Ks[krow * 64 + (((ks * 2 + hi) ^ kphi) * 8)]);
            sac = __builtin_amdgcn_mfma_f32_32x32x16_bf16(kf, aq[ks], sac, 0, 0, 0);
        }

        // p = g(s): one b32 (v0, delta) gather + fma lerp; pack pairs to bf16
        unsigned w[8];
        #pragma unroll
        for (int t = 0; t < 8; t++) {
            float pv[2];
            #pragma unroll
            for (int u = 0; u < 2; u++) {
                float s = sac[t * 2 + u];
                float x = fmaf(s, invh, xoff);
                x = __builtin_amdgcn_fmed3f(x, 0.0f, (float)(NLUT - 1));
                int j = (int)x;
                float f = x - (float)j;
                unsigned pr = lut[j];
                float v0 = __builtin_bit_cast(float, pr << 16);
                float dl = __builtin_bit_cast(float, pr & 0xffff0000u);
                pv[u] = fmaf(f, dl, v0);
            }
            w[t] = cvt_pk_bf16(pv[0], pv[1]);
        }

        // redistribute across lane halves -> PV B-fragments
        plane_swap(w[0], w[2]); plane_swap(w[1], w[3]);
        plane_swap(w[4], w[6]); plane_swap(w[5], w[7]);
        ux4 b0v = {w[0], w[1], w[2], w[3]};
        ux4 b1v = {w[4], w[5], w[6], w[7]};
        bfx8 pb0 = __builtin_bit_cast(bfx8, b0v);
        bfx8 pb1 = __builtin_bit_cast(bfx8, b1v);

        // O^T[dk][q] += VT . P^T   (2 dk-tiles x 2 k-steps)
        #pragma unroll
        for (int dt = 0; dt < 2; dt++) {
            int row = dt * 32 + l31;
            int vphi = (row ^ (row >> 3)) & 7;
            bfx8 v0f = *(const bfx8*)(&Vs[row * 64 + (((st * 4 + 0 + hi) ^ vphi) * 8)]);
            bfx8 v1f = *(const bfx8*)(&Vs[row * 64 + (((st * 4 + 2 + hi) ^ vphi) * 8)]);
            oacc[dt] = __builtin_amdgcn_mfma_f32_32x32x16_bf16(v0f, pb0, oacc[dt], 0, 0, 0);
            oacc[dt] = __builtin_amdgcn_mfma_f32_32x32x16_bf16(v1f, pb1, oacc[dt], 0, 0, 0);
        }
        // den[q] += sum_kv P[kv][q] on the matrix pipe (rows all equal)
        dacc = __builtin_amdgcn_mfma_f32_32x32x16_bf16(ones, pb0, dacc, 0, 0, 0);
        dacc = __builtin_amdgcn_mfma_f32_32x32x16_bf16(ones, pb1, dacc, 0, 0, 0);
    }

    float den = dacc[0];   // den[q=l31] for this wave's kv-half (rows equal)

    // combine kv halves: st=1 waves stash to LDS (Ks/Vs dead), st=0 finalize
    __syncthreads();
    float* obuf = (wq == 0) ? (float*)Ks : (float*)Vs;   // 8 KB each
    if (st == 1) {
        #pragma unroll
        for (int dt = 0; dt < 2; dt++)
            #pragma unroll
            for (int r = 0; r < 16; r++)
                obuf[(dt * 16 + r) * 64 + lane] = oacc[dt][r];
        dbuf[wq * 64 + lane] = den;
    }
    __syncthreads();
    if (st == 0) {
        float dtot = den + dbuf[wq * 64 + lane];
        int b = bh >> 4, h = bh & 15;
        #pragma unroll
        for (int dt = 0; dt < 2; dt++) {
            #pragma unroll
            for (int r = 0; r < 16; r++) {
                float o = oacc[dt][r] + obuf[(dt * 16 + r) * 64 + lane];
                int dk = dt * 32 + (r & 3) + 8 * (r >> 2) + 4 * hi;
                int q = q0 + wq * 32 + l31;
                AO[((size_t)(b * S_LEN + q)) * DMODEL + h * DKH + dk] = f2bf(o / dtot);
            }
        }
    }
}

// ---------------------------------------------------------------------------
extern "C" void kernel_launch(void* const* d_in, const int* in_sizes, int n_in,
                              void* d_out, int out_size, void* d_ws, size_t ws_size,
                              hipStream_t stream) {
    const float* query   = (const float*)d_in[0];
    const float* key_in  = (const float*)d_in[1];
    const float* value   = (const float*)d_in[2];
    const float* w_q     = (const float*)d_in[3];
    const float* b_q     = (const float*)d_in[4];
    const float* w_k     = (const float*)d_in[5];
    const float* b_k     = (const float*)d_in[6];
    const float* w_v     = (const float*)d_in[7];
    const float* b_v     = (const float*)d_in[8];
    const float* w_o     = (const float*)d_in[9];
    const float* b_o     = (const float*)d_in[10];
    const float* centers = (const float*)d_in[11];
    const float* widths  = (const float*)d_in[12];
    const float* temp    = (const float*)d_in[13];

    char* p = (char*)d_ws;
    auto alloc = [&](size_t bytes) -> void* {
        void* r = (void*)p;
        p += (bytes + 255) & ~(size_t)255;
        return r;
    };
    const size_t nBHSD = (size_t)2 * NHEAD * S_LEN * DKH;    // 4.19M elems
    const size_t nW    = (size_t)DMODEL * DMODEL;            // 1.05M elems
    unsigned* lutp = (unsigned*)alloc(NLUT * 4);
    short* Qb  = (short*)alloc(nBHSD * 2);
    short* Kb  = (short*)alloc(nBHSD * 2);
    short* VTb = (short*)alloc(nBHSD * 2);

    char* save = p;
    short* xq  = (short*)alloc(nBHSD * 2);
    short* xk  = (short*)alloc(nBHSD * 2);
    short* xv  = (short*)alloc(nBHSD * 2);
    short* bwq = (short*)alloc(nW * 2);
    short* bwk = (short*)alloc(nW * 2);
    short* bwv = (short*)alloc(nW * 2);
    short* bwo = (short*)alloc(nW * 2);
    bool fused = ((size_t)(p - (char*)d_ws) <= ws_size);

    dim3 blk(256);
    dim3 gq(8, 32, 3), g1(8, 32, 1), fg(32, 32);
    GemmJob JO;

    if (fused) {
        short* AO = xq;   // alias: xq dead after QKV gemm
        prep_all<<<dim3(1032), blk, 0, stream>>>(query, key_in, value, w_q, w_k, w_v, w_o,
                xq, xk, xv, bwq, bwk, bwv, bwo, centers, widths, temp, lutp);
        GemmJob JQ = {xq, bwq, b_q, Qb,  nullptr, 0, 0.125f};   // 1/sqrt(64) folded
        GemmJob JK = {xk, bwk, b_k, Kb,  nullptr, 0, 1.0f};
        GemmJob JV = {xv, bwv, b_v, VTb, nullptr, 1, 1.0f};
        gemm128<<<gq, blk, 0, stream>>>(JQ, JK, JV);
        flash_fuzzy<<<fg, blk, 0, stream>>>(Qb, Kb, VTb, lutp, AO);
        JO = {AO, bwo, b_o, nullptr, (float*)d_out, 2, 1.0f};
        gemm128<<<g1, blk, 0, stream>>>(JO, JO, JO);
    } else {
        // serial fallback: reuse one x-buffer + one w-buffer (~36 MB total)
        p = save;
        short* xf = (short*)alloc(nBHSD * 2);
        short* wb = (short*)alloc(nW * 2);
        short* AO = xf;
        const int n8x = (int)(nBHSD / 8), n8w = (int)(nW / 8);
        dim3 cg((n8x + 255) / 256), cw((n8w + 255) / 256);
        build_lut_pk<<<dim3(8), blk, 0, stream>>>(centers, widths, temp, lutp);
        cast_bf16<<<cg, blk, 0, stream>>>(query, xf, n8x);
        cast_bf16<<<cw, blk, 0, stream>>>(w_q, wb, n8w);
        JO = {xf, wb, b_q, Qb, nullptr, 0, 0.125f};
        gemm128<<<g1, blk, 0, stream>>>(JO, JO, JO);
        cast_bf16<<<cg, blk, 0, stream>>>(key_in, xf, n8x);
        cast_bf16<<<cw, blk, 0, stream>>>(w_k, wb, n8w);
        JO = {xf, wb, b_k, Kb, nullptr, 0, 1.0f};
        gemm128<<<g1, blk, 0, stream>>>(JO, JO, JO);
        cast_bf16<<<cg, blk, 0, stream>>>(value, xf, n8x);
        cast_bf16<<<cw, blk, 0, stream>>>(w_v, wb, n8w);
        JO = {xf, wb, b_v, VTb, nullptr, 1, 1.0f};
        gemm128<<<g1, blk, 0, stream>>>(JO, JO, JO);
        flash_fuzzy<<<fg, blk, 0, stream>>>(Qb, Kb, VTb, lutp, AO);
        cast_bf16<<<cw, blk, 0, stream>>>(w_o, wb, n8w);
        JO = {AO, wb, b_o, nullptr, (float*)d_out, 2, 1.0f};
        gemm128<<<g1, blk, 0, stream>>>(JO, JO, JO);
    }
}